// Round 19
// baseline (858.296 us; speedup 1.0000x reference)
//
#include <hip/hip_runtime.h>
#include <hip/hip_bf16.h>

#define D_MODEL 1024
#define NHEAD 16
#define DK 64
#define DFF 2048
#define SEQ 2048
#define NBATCH 2
#define NTOK (NBATCH*SEQ)

typedef __attribute__((ext_vector_type(8))) short bf16x8;
typedef __attribute__((ext_vector_type(4))) float f32x4;
typedef __attribute__((ext_vector_type(16))) float f32x16;
typedef __attribute__((ext_vector_type(4))) short s16x4;

#if __has_builtin(__builtin_amdgcn_exp2f)
#define EXP2(x) __builtin_amdgcn_exp2f(x)
#else
#define EXP2(x) exp2f(x)
#endif

__device__ __forceinline__ short f2bf(float f) {
    union { float f; unsigned u; } v; v.f = f;
    unsigned r = v.u + 0x7FFFu + ((v.u >> 16) & 1u);
    return (short)(r >> 16);
}

__device__ __forceinline__ float bf2f(short s) {
    union { unsigned u; float f; } v;
    v.u = ((unsigned)(unsigned short)s) << 16;
    return v.f;
}

__device__ __forceinline__ void gld16(void* lds, const void* g) {
    __builtin_amdgcn_global_load_lds(
        (const __attribute__((address_space(1))) void*)g,
        (__attribute__((address_space(3))) void*)lds, 16, 0, 0);
}

// ---------------- fused prologue: 6 weight transposes + LN1 in ONE dispatch ----------------
struct TP6 { const float* src[6]; short* dst[6]; int K[6], N[6], nx[6]; };
__global__ __launch_bounds__(256) void k_prolog(TP6 tp, const float* __restrict__ x,
                                                const float* __restrict__ g,
                                                const float* __restrict__ bta,
                                                short* __restrict__ y)
{
    __shared__ float t[32][33];
    int id = blockIdx.x;
    if (id >= 8192) {
        int row = (id - 8192) * 4 + (threadIdx.x >> 6);
        int lane = threadIdx.x & 63;
        const float* xr = x + (size_t)row * D_MODEL;
        float4 v[4];
        float s = 0.f, s2 = 0.f;
#pragma unroll
        for (int c = 0; c < 4; ++c) {
            v[c] = *(const float4*)(xr + c * 256 + lane * 4);
            s  += v[c].x + v[c].y + v[c].z + v[c].w;
            s2 += v[c].x * v[c].x + v[c].y * v[c].y + v[c].z * v[c].z + v[c].w * v[c].w;
        }
#pragma unroll
        for (int off = 1; off < 64; off <<= 1) {
            s  += __shfl_xor(s, off, 64);
            s2 += __shfl_xor(s2, off, 64);
        }
        float mean = s * (1.f / 1024.f);
        float var  = s2 * (1.f / 1024.f) - mean * mean;
        float rs = rsqrtf(var + 1e-5f);
        short* yr = y + (size_t)row * D_MODEL;
#pragma unroll
        for (int c = 0; c < 4; ++c) {
            int idx = c * 256 + lane * 4;
            float4 gg = *(const float4*)(g + idx);
            float4 bb = *(const float4*)(bta + idx);
            s16x4 o;
            o.x = f2bf((v[c].x - mean) * rs * gg.x + bb.x);
            o.y = f2bf((v[c].y - mean) * rs * gg.y + bb.y);
            o.z = f2bf((v[c].z - mean) * rs * gg.z + bb.z);
            o.w = f2bf((v[c].w - mean) * rs * gg.w + bb.w);
            *(s16x4*)(yr + idx) = o;
        }
        return;
    }
    int seg, tt;
    if (id < 4096)      { seg = id >> 10; tt = id & 1023; }
    else if (id < 6144) { seg = 4; tt = id - 4096; }
    else                { seg = 5; tt = id - 6144; }
    const float* W = tp.src[seg];
    short* WT = tp.dst[seg];
    int K = tp.K[seg], N = tp.N[seg], nx = tp.nx[seg];
    int bx = tt % nx, by = tt / nx;
    int tid = threadIdx.x;
    int n0 = bx * 32, k0 = by * 32;
#pragma unroll
    for (int p = 0; p < 4; ++p) {
        int idx = p * 256 + tid, r = idx >> 5, c = idx & 31;
        t[r][c] = W[(size_t)(k0 + r) * N + (n0 + c)];
    }
    __syncthreads();
#pragma unroll
    for (int p = 0; p < 4; ++p) {
        int idx = p * 256 + tid, r = idx >> 5, c = idx & 31;
        WT[(size_t)(n0 + r) * K + (k0 + c)] = f2bf(t[c][r]);
    }
}

// ---------------- LayerNorm over bf16 input -> bf16 out, one wave per row ----------------
__global__ __launch_bounds__(256) void k_layernorm_bf(const short* __restrict__ x,
                                                      const float* __restrict__ g,
                                                      const float* __restrict__ bta,
                                                      short* __restrict__ y)
{
    int row = blockIdx.x * 4 + (threadIdx.x >> 6);
    int lane = threadIdx.x & 63;
    const short* xr = x + (size_t)row * D_MODEL;
    float v[16];
    float s = 0.f, s2 = 0.f;
#pragma unroll
    for (int c = 0; c < 2; ++c) {
        bf16x8 raw = *(const bf16x8*)(xr + c * 512 + lane * 8);
#pragma unroll
        for (int j = 0; j < 8; ++j) {
            float f = bf2f(raw[j]);
            v[c * 8 + j] = f;
            s += f;
            s2 += f * f;
        }
    }
#pragma unroll
    for (int off = 1; off < 64; off <<= 1) {
        s  += __shfl_xor(s, off, 64);
        s2 += __shfl_xor(s2, off, 64);
    }
    float mean = s * (1.f / 1024.f);
    float var  = s2 * (1.f / 1024.f) - mean * mean;
    float rs = rsqrtf(var + 1e-5f);
    short* yr = y + (size_t)row * D_MODEL;
#pragma unroll
    for (int c = 0; c < 2; ++c) {
        int base = c * 512 + lane * 8;
        float4 g0 = *(const float4*)(g + base);
        float4 g1 = *(const float4*)(g + base + 4);
        float4 b0 = *(const float4*)(bta + base);
        float4 b1 = *(const float4*)(bta + base + 4);
        s16x4 o0, o1;
        o0.x = f2bf((v[c*8+0] - mean) * rs * g0.x + b0.x);
        o0.y = f2bf((v[c*8+1] - mean) * rs * g0.y + b0.y);
        o0.z = f2bf((v[c*8+2] - mean) * rs * g0.z + b0.z);
        o0.w = f2bf((v[c*8+3] - mean) * rs * g0.w + b0.w);
        o1.x = f2bf((v[c*8+4] - mean) * rs * g1.x + b1.x);
        o1.y = f2bf((v[c*8+5] - mean) * rs * g1.y + b1.y);
        o1.z = f2bf((v[c*8+6] - mean) * rs * g1.z + b1.z);
        o1.w = f2bf((v[c*8+7] - mean) * rs * g1.w + b1.w);
        *(s16x4*)(yr + base) = o0;
        *(s16x4*)(yr + base + 4) = o1;
    }
}

// ---------------- GEMM: r18 config ----------------
template<int EPI, int BN, int THREADS>
__global__ __launch_bounds__(THREADS, (THREADS == 512) ? 8 : 4) void k_gemm(
    const short* __restrict__ A, const short* __restrict__ BT, int N, int K,
    const float* __restrict__ bias, const float* __restrict__ bias2, const float* __restrict__ bias3,
    const float* __restrict__ resid, float* __restrict__ outF,
    short* __restrict__ outB, short* __restrict__ outQ, short* __restrict__ outK, short* __restrict__ outV)
{
    constexpr int CW = (THREADS == 512) ? 4 : 2;   // column-waves
    constexpr int NBUF = (THREADS == 512) ? 2 : 3;
    __shared__ __align__(16) short sA[NBUF][128 * 32];
    __shared__ __align__(16) short sB[NBUF][BN * 32];
    int tid = threadIdx.x;
    int lane = tid & 63, wid = tid >> 6;
    int wr = wid / CW, wc = wid % CW;
    int l31 = lane & 31, hi = lane >> 5;

    int gx = gridDim.x;
    int nwg = gx * gridDim.y;
    int orig = blockIdx.x + blockIdx.y * gx;
    int wg = (orig & 7) * (nwg >> 3) + (orig >> 3);   // nwg % 8 == 0 for all our grids
    int bx = wg % gx, by = wg / gx;

    const short* Ab = A + (size_t)by * 128 * K;
    const short* Bb = BT + (size_t)bx * BN * K;

    auto src = [&](const short* base, int cc) {
        int r = cc >> 2, s = cc & 3;
        return (const char*)(base + (size_t)r * K) + ((s ^ ((r >> 1) & 3)) << 4);
    };
    const char *pA0 = src(Ab, tid), *pA1 = nullptr, *pB0;
    if constexpr (THREADS == 512) {
        pB0 = src(Bb, tid);
    } else {
        pA1 = src(Ab, 256 + tid);
        pB0 = src(Bb, tid & (BN * 4 - 1));
    }

    auto stage = [&](int buf) {
        if constexpr (THREADS == 512) {
            gld16(&sA[buf][tid * 8], pA0);  pA0 += 64;
            gld16(&sB[buf][tid * 8], pB0);  pB0 += 64;
        } else {
            gld16(&sA[buf][tid * 8], pA0);          pA0 += 64;
            gld16(&sA[buf][(256 + tid) * 8], pA1);  pA1 += 64;
            gld16(&sB[buf][(tid & (BN * 4 - 1)) * 8], pB0);  pB0 += 64;
        }
    };

    f32x16 acc0 = {0,0,0,0,0,0,0,0,0,0,0,0,0,0,0,0};
    f32x16 acc1 = {0,0,0,0,0,0,0,0,0,0,0,0,0,0,0,0};

    const int NT = K / 32;
    int cur = 0;
    stage(0);
    if constexpr (NBUF == 3) stage(1);
    for (int t = 0; t < NT; ++t) {
        if constexpr (NBUF == 2) {
            if (t + 1 < NT) {
                stage(cur ^ 1);
                asm volatile("s_waitcnt vmcnt(2)" ::: "memory");
            } else {
                asm volatile("s_waitcnt vmcnt(0)" ::: "memory");
            }
        } else {
            if (t + 2 < NT) {
                int nb3 = cur + 2; if (nb3 >= 3) nb3 -= 3;
                stage(nb3);
                asm volatile("s_waitcnt vmcnt(6)" ::: "memory");
            } else if (t + 1 < NT) {
                asm volatile("s_waitcnt vmcnt(3)" ::: "memory");
            } else {
                asm volatile("s_waitcnt vmcnt(0)" ::: "memory");
            }
        }
        __builtin_amdgcn_s_barrier();
        int rb = wc * 32 + l31;
        int swb = (rb >> 1) & 3;
        bf16x8 b0 = *(const bf16x8*)((const char*)sB[cur] + rb * 64 + ((hi ^ swb) << 4));
        bf16x8 b1 = *(const bf16x8*)((const char*)sB[cur] + rb * 64 + (((2 + hi) ^ swb) << 4));
        {
            int ra = wr * 64 + l31;
            int swa = (ra >> 1) & 3;
            bf16x8 a0 = *(const bf16x8*)((const char*)sA[cur] + ra * 64 + ((hi ^ swa) << 4));
            acc0 = __builtin_amdgcn_mfma_f32_32x32x16_bf16(a0, b0, acc0, 0, 0, 0);
            bf16x8 a1 = *(const bf16x8*)((const char*)sA[cur] + ra * 64 + (((2 + hi) ^ swa) << 4));
            acc0 = __builtin_amdgcn_mfma_f32_32x32x16_bf16(a1, b1, acc0, 0, 0, 0);
        }
        {
            int ra = wr * 64 + 32 + l31;
            int swa = (ra >> 1) & 3;
            bf16x8 a0 = *(const bf16x8*)((const char*)sA[cur] + ra * 64 + ((hi ^ swa) << 4));
            acc1 = __builtin_amdgcn_mfma_f32_32x32x16_bf16(a0, b0, acc1, 0, 0, 0);
            bf16x8 a1 = *(const bf16x8*)((const char*)sA[cur] + ra * 64 + (((2 + hi) ^ swa) << 4));
            acc1 = __builtin_amdgcn_mfma_f32_32x32x16_bf16(a1, b1, acc1, 0, 0, 0);
        }
        __builtin_amdgcn_s_barrier();
        ++cur; if (cur >= NBUF) cur = 0;
    }

    int n = bx * BN + wc * 32 + l31;
    int mb = by * 128 + wr * 64 + 4 * hi;
    if constexpr (EPI == 0) {
        int seg = n >> 10, nn = n & 1023;
        int h = nn >> 6, dd = nn & 63;
        int bb = (by * 128) >> 11;
        if (seg == 0) {
            float bs = bias[nn];
            short* p = outQ + (size_t)(bb * NHEAD + h) * SEQ * DK + dd;
#pragma unroll
            for (int i = 0; i < 2; ++i)
#pragma unroll
                for (int reg = 0; reg < 16; ++reg) {
                    int ss = (mb + i * 32 + (reg & 3) + 8 * (reg >> 2)) & 2047;
                    float v = (i == 0) ? acc0[reg] : acc1[reg];
                    p[(size_t)ss * DK] = f2bf((v + bs) * 0.18033688011112042f);
                }
        } else if (seg == 1) {
            float bs = bias2[nn];
            short* p = outK + (size_t)(bb * NHEAD + h) * SEQ * DK + dd;
#pragma unroll
            for (int i = 0; i < 2; ++i)
#pragma unroll
                for (int reg = 0; reg < 16; ++reg) {
                    int ss = (mb + i * 32 + (reg & 3) + 8 * (reg >> 2)) & 2047;
                    float v = (i == 0) ? acc0[reg] : acc1[reg];
                    p[(size_t)ss * DK] = f2bf(v + bs);
                }
        } else {
            float bs = bias3[nn];
            short* p = outV + ((size_t)(bb * NHEAD + h) * DK + dd) * SEQ;
#pragma unroll
            for (int i = 0; i < 2; ++i)
#pragma unroll
                for (int reg = 0; reg < 16; ++reg) {
                    int ss = (mb + i * 32 + (reg & 3) + 8 * (reg >> 2)) & 2047;
                    float v = (i == 0) ? acc0[reg] : acc1[reg];
                    p[ss] = f2bf(v + bs);
                }
        }
    } else if constexpr (EPI == 1) {
        float bs = bias[n];
#pragma unroll
        for (int i = 0; i < 2; ++i)
#pragma unroll
            for (int reg = 0; reg < 16; ++reg) {
                int m = mb + i * 32 + (reg & 3) + 8 * (reg >> 2);
                float v = (i == 0) ? acc0[reg] : acc1[reg];
                size_t idx = (size_t)m * N + n;
                outB[idx] = f2bf(v + bs + resid[idx]);
            }
    } else if constexpr (EPI == 3) {
        const short* rb16 = (const short*)resid;
        float bs = bias[n];
#pragma unroll
        for (int i = 0; i < 2; ++i)
#pragma unroll
            for (int reg = 0; reg < 16; ++reg) {
                int m = mb + i * 32 + (reg & 3) + 8 * (reg >> 2);
                float v = (i == 0) ? acc0[reg] : acc1[reg];
                size_t idx = (size_t)m * N + n;
                outF[idx] = v + bs + bf2f(rb16[idx]);
            }
    } else {
        float bs = bias[n];
#pragma unroll
        for (int i = 0; i < 2; ++i)
#pragma unroll
            for (int reg = 0; reg < 16; ++reg) {
                int m = mb + i * 32 + (reg & 3) + 8 * (reg >> 2);
                float v = (i == 0) ? acc0[reg] : acc1[reg];
                float r2 = v + bs;
                outB[(size_t)m * N + n] = f2bf(r2 > 0.f ? r2 : 0.f);
            }
    }
}

// ---------------- flash attention: r17 structure + Ls-MFMA row-sums ----------------
// 8 waves = 4 q-groups x 2 k-halves, 512 threads, 128 q-rows/block.
// Row-sums via Ls = mfma(P, ones, Ls): lands in the SAME register layout as Oa
// (m = (reg&3)+8*(reg>>2)+4*hi), deleting 16 VALU adds/tile, the lane-split
// shfl_xor, and all 16 epilogue shuffles. VGPR 48+16 = ~64 -> still in the
// 8-waves/SIMD band (LB(512,8) pins the allocator). Ls is lane-invariant per
// hi-half, so the ks=1 wave publishes it via a 512B LDS side-region.
__global__ __launch_bounds__(512, 8) void k_attn(const short* __restrict__ Q, const short* __restrict__ Kk,
                                                 const short* __restrict__ Vt, short* __restrict__ Operm)
{
    __shared__ __align__(16) union {
        short kv[2][2][64 * 64];        // [buf][K/V][tile] 32 KB
        float mrg[4 * 64 * 33];         // O merge scratch 33.8 KB
    } sU;
    __shared__ float sLs[4][2][16];     // ks=1 row-sums [qg][hi][reg]
    int tid = threadIdx.x, lane = tid & 63;
    int wid = tid >> 6;
    int qg = wid >> 1, ks = wid & 1;
    int l31 = lane & 31, hi = lane >> 5;

    int orig = blockIdx.x + blockIdx.y * 32;
    int lg = (orig & 7) * 64 + (orig >> 3);   // 512 blocks: XCD gets 4 consecutive bh
    int bh = lg >> 4, qt = lg & 15;
    int b = bh >> 4, h = bh & 15;
    int q0 = qt * 128 + qg * 32;
    const short* Qp = Q + (size_t)bh * SEQ * DK;
    const short* Kp = Kk + (size_t)bh * SEQ * DK;
    const short* Vp = Vt + (size_t)bh * DK * SEQ;

    bf16x8 qf[4];
#pragma unroll
    for (int kb = 0; kb < 4; ++kb)
        qf[kb] = *(const bf16x8*)(Qp + (size_t)(q0 + l31) * DK + kb * 16 + hi * 8);

    const short one_bf = (short)0x3F80;
    const bf16x8 onesf = {one_bf, one_bf, one_bf, one_bf, one_bf, one_bf, one_bf, one_bf};

    int r0 = tid >> 3;
    int lb = ((tid & 7) ^ (r0 & 7)) << 4;
    const char* pK0 = (const char*)(Kp + (size_t)r0 * DK) + lb;
    const char* pV0 = (const char*)(Vp + (size_t)r0 * SEQ) + lb;

    auto stage = [&](int buf) {
        gld16(&sU.kv[buf][0][tid * 8], pK0);  pK0 += 8192;
        gld16(&sU.kv[buf][1][tid * 8], pV0);  pV0 += 128;
    };

    f32x16 Oa0 = {0,0,0,0,0,0,0,0,0,0,0,0,0,0,0,0};
    f32x16 Oa1 = {0,0,0,0,0,0,0,0,0,0,0,0,0,0,0,0};
    f32x16 Ls  = {0,0,0,0,0,0,0,0,0,0,0,0,0,0,0,0};

    stage(0);
    const int NT = SEQ / 64;
    int krow = ks * 32 + l31;
    int sw = (l31 & 7) << 4;
    for (int t = 0; t < NT; ++t) {
        int cur = t & 1;
        if (t + 1 < NT) {
            stage(cur ^ 1);
            asm volatile("s_waitcnt vmcnt(2)" ::: "memory");   // tile t's 2 loads done
        } else {
            asm volatile("s_waitcnt vmcnt(0)" ::: "memory");
        }
        __builtin_amdgcn_s_barrier();
        const char* sKc = (const char*)sU.kv[cur][0];
        const char* sVc = (const char*)sU.kv[cur][1];

        f32x16 sc = {0,0,0,0,0,0,0,0,0,0,0,0,0,0,0,0};
        __builtin_amdgcn_s_setprio(1);
#pragma unroll
        for (int kb = 0; kb < 4; ++kb) {
            int cb = (kb * 32 + hi * 16) ^ sw;
            bf16x8 kf = *(const bf16x8*)(sKc + krow * 128 + cb);
            sc = __builtin_amdgcn_mfma_f32_32x32x16_bf16(kf, qf[kb], sc, 0, 0, 0);
        }
        __builtin_amdgcn_s_setprio(0);

        unsigned W[4][2];
#pragma unroll
        for (int tt = 0; tt < 4; ++tt) {
            float pa_ = EXP2(sc[4*tt+0]), pb_ = EXP2(sc[4*tt+1]);
            float pc_ = EXP2(sc[4*tt+2]), pd_ = EXP2(sc[4*tt+3]);
            asm("v_cvt_pk_bf16_f32 %0, %1, %2" : "=v"(W[tt][0]) : "v"(pa_), "v"(pb_));
            asm("v_cvt_pk_bf16_f32 %0, %1, %2" : "=v"(W[tt][1]) : "v"(pc_), "v"(pd_));
        }

        auto pv_step = [&](unsigned a0, unsigned a1, unsigned b0v, unsigned b1v, int kslice) {
            asm("v_permlane32_swap_b32 %0, %1" : "+v"(a0), "+v"(b0v));
            asm("v_permlane32_swap_b32 %0, %1" : "+v"(a1), "+v"(b1v));
            union { unsigned u[4]; bf16x8 v; } pa;
            pa.u[0] = a0; pa.u[1] = a1; pa.u[2] = b0v; pa.u[3] = b1v;
            int cb = (kslice * 32 + hi * 16) ^ sw;
            bf16x8 vf0 = *(const bf16x8*)(sVc + l31 * 128 + cb);
            bf16x8 vf1 = *(const bf16x8*)(sVc + (32 + l31) * 128 + cb);
            Oa0 = __builtin_amdgcn_mfma_f32_32x32x16_bf16(pa.v, vf0, Oa0, 0, 0, 0);
            Oa1 = __builtin_amdgcn_mfma_f32_32x32x16_bf16(pa.v, vf1, Oa1, 0, 0, 0);
            Ls  = __builtin_amdgcn_mfma_f32_32x32x16_bf16(pa.v, onesf, Ls, 0, 0, 0);
        };
        __builtin_amdgcn_s_setprio(1);
        pv_step(W[0][0], W[0][1], W[1][0], W[1][1], ks * 2 + 0);
        pv_step(W[2][0], W[2][1], W[3][0], W[3][1], ks * 2 + 1);
        __builtin_amdgcn_s_setprio(0);
        __builtin_amdgcn_s_barrier();
    }

    // cross-wave merge of the two k-halves (exact: plain adds).
    // Ls is lane-invariant within each hi-half: ks=1 lanes 0 and 32 publish it.
    float* mrg = sU.mrg;
    if (ks == 1) {
        float* m0 = mrg + (qg * 64 + lane) * 33;
#pragma unroll
        for (int i = 0; i < 16; ++i) m0[i] = Oa0[i];
#pragma unroll
        for (int i = 0; i < 16; ++i) m0[16 + i] = Oa1[i];
        if (l31 == 0) {
#pragma unroll
            for (int i = 0; i < 16; ++i) sLs[qg][hi][i] = Ls[i];
        }
    }
    __syncthreads();
    if (ks == 0) {
        const float* m0 = mrg + (qg * 64 + lane) * 33;
#pragma unroll
        for (int i = 0; i < 16; ++i) Oa0[i] += m0[i];
#pragma unroll
        for (int i = 0; i < 16; ++i) Oa1[i] += m0[16 + i];

        float rlv[16];
#pragma unroll
        for (int i = 0; i < 16; ++i) rlv[i] = 1.f / (Ls[i] + sLs[qg][hi][i]);

        int qcol = (q0 & 1023) + 4 * hi;
        int qhi = q0 >> 10;
#pragma unroll
        for (int db = 0; db < 2; ++db) {
            const f32x16& O = db ? Oa1 : Oa0;
            int dd = db * 32 + l31;
            size_t rowoff = ((size_t)b * SEQ + h * 128 + 2 * dd + qhi) * D_MODEL + qcol;
#pragma unroll
            for (int tt = 0; tt < 4; ++tt) {
                s16x4 o;
                o.x = f2bf(O[4*tt+0] * rlv[4*tt+0]);
                o.y = f2bf(O[4*tt+1] * rlv[4*tt+1]);
                o.z = f2bf(O[4*tt+2] * rlv[4*tt+2]);
                o.w = f2bf(O[4*tt+3] * rlv[4*tt+3]);
                *(s16x4*)(Operm + rowoff + 8 * tt) = o;
            }
        }
    }
}

extern "C" void kernel_launch(void* const* d_in, const int* in_sizes, int n_in,
                              void* d_out, int out_size, void* d_ws, size_t ws_size,
                              hipStream_t stream)
{
    const float* x   = (const float*)d_in[0];
    const float* Wq  = (const float*)d_in[1];
    const float* bq  = (const float*)d_in[2];
    const float* Wk  = (const float*)d_in[3];
    const float* bk  = (const float*)d_in[4];
    const float* Wv  = (const float*)d_in[5];
    const float* bv  = (const float*)d_in[6];
    const float* Wo  = (const float*)d_in[7];
    const float* bo  = (const float*)d_in[8];
    const float* g1  = (const float*)d_in[9];
    const float* b1l = (const float*)d_in[10];
    const float* g2  = (const float*)d_in[11];
    const float* b2l = (const float*)d_in[12];
    const float* W1  = (const float*)d_in[13];
    const float* b1  = (const float*)d_in[14];
    const float* W2  = (const float*)d_in[15];
    const float* b2  = (const float*)d_in[16];
    float* out = (float*)d_out;

    char* ws = (char*)d_ws;
    size_t off = 0;
    auto alloc = [&](size_t bytes) {
        char* p = ws + off;
        off += (bytes + 255) & ~(size_t)255;
        return p;
    };
    short* WqkvT = (short*)alloc((size_t)3072 * 1024 * 2);
    short* WoT   = (short*)alloc((size_t)1024 * 1024 * 2);
    short* W1T   = (short*)alloc((size_t)2048 * 1024 * 2);
    short* W2T   = (short*)alloc((size_t)1024 * 2048 * 2);
    short* Y     = (short*)alloc((size_t)NTOK * 1024 * 2);
    short* Qb    = (short*)alloc((size_t)NTOK * 1024 * 2);
    short* Kb    = (short*)alloc((size_t)NTOK * 1024 * 2);
    short* Vtb   = (short*)alloc((size_t)NTOK * 1024 * 2);
    short* Operm = (short*)alloc((size_t)NTOK * 1024 * 2);
    short* Xb    = (short*)alloc((size_t)NTOK * 1024 * 2);   // bf16 x2 residual
    short* F1    = (short*)alloc((size_t)NTOK * 2048 * 2);

    // fused prologue: 6 weight transposes + LN1 in one dispatch
    TP6 tp;
    tp.src[0] = Wq; tp.dst[0] = WqkvT;                tp.K[0] = 1024; tp.N[0] = 1024; tp.nx[0] = 32;
    tp.src[1] = Wk; tp.dst[1] = WqkvT + 1024 * 1024;  tp.K[1] = 1024; tp.N[1] = 1024; tp.nx[1] = 32;
    tp.src[2] = Wv; tp.dst[2] = WqkvT + 2048 * 1024;  tp.K[2] = 1024; tp.N[2] = 1024; tp.nx[2] = 32;
    tp.src[3] = Wo; tp.dst[3] = WoT;                  tp.K[3] = 1024; tp.N[3] = 1024; tp.nx[3] = 32;
    tp.src[4] = W1; tp.dst[4] = W1T;                  tp.K[4] = 1024; tp.N[4] = 2048; tp.nx[4] = 64;
    tp.src[5] = W2; tp.dst[5] = W2T;                  tp.K[5] = 2048; tp.N[5] = 1024; tp.nx[5] = 32;
    k_prolog<<<8192 + 1024, 256, 0, stream>>>(tp, x, g1, b1l, Y);

    // fused QKV GEMM (4096 x 3072 x 1024), 512 threads, 8 waves, 2-buf
    k_gemm<0,128,512><<<dim3(24, 32), 512, 0, stream>>>(Y, WqkvT, 3072, 1024,
        bq, bk, bv, nullptr, nullptr, nullptr, Qb, Kb, Vtb);

    // attention (512 blocks, 512 threads: 4 q-groups x 2 k-halves)
    k_attn<<<dim3(32, 16), 512, 0, stream>>>(Qb, Kb, Vtb, Operm);

    // Wo GEMM + bias + residual(x) -> Xb (bf16)   [BN=64 -> 512 blocks]
    k_gemm<1,64,256><<<dim3(16, 32), 256, 0, stream>>>(Operm, WoT, 1024, 1024,
        bo, nullptr, nullptr, x, nullptr, Xb, nullptr, nullptr, nullptr);

    // LN2: Xb (bf16) -> Y (bf16)
    k_layernorm_bf<<<NTOK / 4, 256, 0, stream>>>(Xb, g2, b2l, Y);

    // FFN1: relu(Y @ W1 + b1) -> F1 (bf16), 512 threads, 8 waves, 2-buf
    k_gemm<2,128,512><<<dim3(16, 32), 512, 0, stream>>>(Y, W1T, 2048, 1024,
        b1, nullptr, nullptr, nullptr, nullptr, F1, nullptr, nullptr, nullptr);

    // FFN2: F1 @ W2 + b2 + Xb(bf16) -> out (fp32)   [BN=64 -> 512 blocks]
    k_gemm<3,64,256><<<dim3(16, 32), 256, 0, stream>>>(F1, W2T, 1024, 2048,
        b2, nullptr, nullptr, (const float*)Xb, out, nullptr, nullptr, nullptr, nullptr);
}

// Round 20
// 180.077 us; speedup vs baseline: 4.7663x; 4.7663x over previous
//
#include <hip/hip_runtime.h>
#include <hip/hip_bf16.h>

#define D_MODEL 1024
#define NHEAD 16
#define DK 64
#define DFF 2048
#define SEQ 2048
#define NBATCH 2
#define NTOK (NBATCH*SEQ)

typedef __attribute__((ext_vector_type(8))) short bf16x8;
typedef __attribute__((ext_vector_type(4))) float f32x4;
typedef __attribute__((ext_vector_type(16))) float f32x16;
typedef __attribute__((ext_vector_type(4))) short s16x4;

#if __has_builtin(__builtin_amdgcn_exp2f)
#define EXP2(x) __builtin_amdgcn_exp2f(x)
#else
#define EXP2(x) exp2f(x)
#endif

__device__ __forceinline__ short f2bf(float f) {
    union { float f; unsigned u; } v; v.f = f;
    unsigned r = v.u + 0x7FFFu + ((v.u >> 16) & 1u);
    return (short)(r >> 16);
}

__device__ __forceinline__ float bf2f(short s) {
    union { unsigned u; float f; } v;
    v.u = ((unsigned)(unsigned short)s) << 16;
    return v.f;
}

__device__ __forceinline__ void gld16(void* lds, const void* g) {
    __builtin_amdgcn_global_load_lds(
        (const __attribute__((address_space(1))) void*)g,
        (__attribute__((address_space(3))) void*)lds, 16, 0, 0);
}

// ---------------- fused prologue: 6 weight transposes + LN1 in ONE dispatch ----------------
struct TP6 { const float* src[6]; short* dst[6]; int K[6], N[6], nx[6]; };
__global__ __launch_bounds__(256) void k_prolog(TP6 tp, const float* __restrict__ x,
                                                const float* __restrict__ g,
                                                const float* __restrict__ bta,
                                                short* __restrict__ y)
{
    __shared__ float t[32][33];
    int id = blockIdx.x;
    if (id >= 8192) {
        int row = (id - 8192) * 4 + (threadIdx.x >> 6);
        int lane = threadIdx.x & 63;
        const float* xr = x + (size_t)row * D_MODEL;
        float4 v[4];
        float s = 0.f, s2 = 0.f;
#pragma unroll
        for (int c = 0; c < 4; ++c) {
            v[c] = *(const float4*)(xr + c * 256 + lane * 4);
            s  += v[c].x + v[c].y + v[c].z + v[c].w;
            s2 += v[c].x * v[c].x + v[c].y * v[c].y + v[c].z * v[c].z + v[c].w * v[c].w;
        }
#pragma unroll
        for (int off = 1; off < 64; off <<= 1) {
            s  += __shfl_xor(s, off, 64);
            s2 += __shfl_xor(s2, off, 64);
        }
        float mean = s * (1.f / 1024.f);
        float var  = s2 * (1.f / 1024.f) - mean * mean;
        float rs = rsqrtf(var + 1e-5f);
        short* yr = y + (size_t)row * D_MODEL;
#pragma unroll
        for (int c = 0; c < 4; ++c) {
            int idx = c * 256 + lane * 4;
            float4 gg = *(const float4*)(g + idx);
            float4 bb = *(const float4*)(bta + idx);
            s16x4 o;
            o.x = f2bf((v[c].x - mean) * rs * gg.x + bb.x);
            o.y = f2bf((v[c].y - mean) * rs * gg.y + bb.y);
            o.z = f2bf((v[c].z - mean) * rs * gg.z + bb.z);
            o.w = f2bf((v[c].w - mean) * rs * gg.w + bb.w);
            *(s16x4*)(yr + idx) = o;
        }
        return;
    }
    int seg, tt;
    if (id < 4096)      { seg = id >> 10; tt = id & 1023; }
    else if (id < 6144) { seg = 4; tt = id - 4096; }
    else                { seg = 5; tt = id - 6144; }
    const float* W = tp.src[seg];
    short* WT = tp.dst[seg];
    int K = tp.K[seg], N = tp.N[seg], nx = tp.nx[seg];
    int bx = tt % nx, by = tt / nx;
    int tid = threadIdx.x;
    int n0 = bx * 32, k0 = by * 32;
#pragma unroll
    for (int p = 0; p < 4; ++p) {
        int idx = p * 256 + tid, r = idx >> 5, c = idx & 31;
        t[r][c] = W[(size_t)(k0 + r) * N + (n0 + c)];
    }
    __syncthreads();
#pragma unroll
    for (int p = 0; p < 4; ++p) {
        int idx = p * 256 + tid, r = idx >> 5, c = idx & 31;
        WT[(size_t)(n0 + r) * K + (k0 + c)] = f2bf(t[c][r]);
    }
}

// ---------------- LayerNorm over bf16 input -> bf16 out, one wave per row ----------------
__global__ __launch_bounds__(256) void k_layernorm_bf(const short* __restrict__ x,
                                                      const float* __restrict__ g,
                                                      const float* __restrict__ bta,
                                                      short* __restrict__ y)
{
    int row = blockIdx.x * 4 + (threadIdx.x >> 6);
    int lane = threadIdx.x & 63;
    const short* xr = x + (size_t)row * D_MODEL;
    float v[16];
    float s = 0.f, s2 = 0.f;
#pragma unroll
    for (int c = 0; c < 2; ++c) {
        bf16x8 raw = *(const bf16x8*)(xr + c * 512 + lane * 8);
#pragma unroll
        for (int j = 0; j < 8; ++j) {
            float f = bf2f(raw[j]);
            v[c * 8 + j] = f;
            s += f;
            s2 += f * f;
        }
    }
#pragma unroll
    for (int off = 1; off < 64; off <<= 1) {
        s  += __shfl_xor(s, off, 64);
        s2 += __shfl_xor(s2, off, 64);
    }
    float mean = s * (1.f / 1024.f);
    float var  = s2 * (1.f / 1024.f) - mean * mean;
    float rs = rsqrtf(var + 1e-5f);
    short* yr = y + (size_t)row * D_MODEL;
#pragma unroll
    for (int c = 0; c < 2; ++c) {
        int base = c * 512 + lane * 8;
        float4 g0 = *(const float4*)(g + base);
        float4 g1 = *(const float4*)(g + base + 4);
        float4 b0 = *(const float4*)(bta + base);
        float4 b1 = *(const float4*)(bta + base + 4);
        s16x4 o0, o1;
        o0.x = f2bf((v[c*8+0] - mean) * rs * g0.x + b0.x);
        o0.y = f2bf((v[c*8+1] - mean) * rs * g0.y + b0.y);
        o0.z = f2bf((v[c*8+2] - mean) * rs * g0.z + b0.z);
        o0.w = f2bf((v[c*8+3] - mean) * rs * g0.w + b0.w);
        o1.x = f2bf((v[c*8+4] - mean) * rs * g1.x + b1.x);
        o1.y = f2bf((v[c*8+5] - mean) * rs * g1.y + b1.y);
        o1.z = f2bf((v[c*8+6] - mean) * rs * g1.z + b1.z);
        o1.w = f2bf((v[c*8+7] - mean) * rs * g1.w + b1.w);
        *(s16x4*)(yr + base) = o0;
        *(s16x4*)(yr + base + 4) = o1;
    }
}

// ---------------- GEMM: r18 config ----------------
// THREADS=512 (BN=128): 8 waves (2x4), 2-buf (32KB), stage->vmcnt(2)->barrier.
// THREADS=256 (BN=64): 4 waves (2x2), 3-buf. 32x32x16 MFMA, wave tile 64x32,
// both-sides XOR swizzle: slot s of row r holds global chunk s^((r>>1)&3).
template<int EPI, int BN, int THREADS>
__global__ __launch_bounds__(THREADS, (THREADS == 512) ? 8 : 4) void k_gemm(
    const short* __restrict__ A, const short* __restrict__ BT, int N, int K,
    const float* __restrict__ bias, const float* __restrict__ bias2, const float* __restrict__ bias3,
    const float* __restrict__ resid, float* __restrict__ outF,
    short* __restrict__ outB, short* __restrict__ outQ, short* __restrict__ outK, short* __restrict__ outV)
{
    constexpr int CW = (THREADS == 512) ? 4 : 2;   // column-waves
    constexpr int NBUF = (THREADS == 512) ? 2 : 3;
    __shared__ __align__(16) short sA[NBUF][128 * 32];
    __shared__ __align__(16) short sB[NBUF][BN * 32];
    int tid = threadIdx.x;
    int lane = tid & 63, wid = tid >> 6;
    int wr = wid / CW, wc = wid % CW;
    int l31 = lane & 31, hi = lane >> 5;

    int gx = gridDim.x;
    int nwg = gx * gridDim.y;
    int orig = blockIdx.x + blockIdx.y * gx;
    int wg = (orig & 7) * (nwg >> 3) + (orig >> 3);   // nwg % 8 == 0 for all our grids
    int bx = wg % gx, by = wg / gx;

    const short* Ab = A + (size_t)by * 128 * K;
    const short* Bb = BT + (size_t)bx * BN * K;

    auto src = [&](const short* base, int cc) {
        int r = cc >> 2, s = cc & 3;
        return (const char*)(base + (size_t)r * K) + ((s ^ ((r >> 1) & 3)) << 4);
    };
    const char *pA0 = src(Ab, tid), *pA1 = nullptr, *pB0;
    if constexpr (THREADS == 512) {
        pB0 = src(Bb, tid);
    } else {
        pA1 = src(Ab, 256 + tid);
        pB0 = src(Bb, tid & (BN * 4 - 1));
    }

    auto stage = [&](int buf) {
        if constexpr (THREADS == 512) {
            gld16(&sA[buf][tid * 8], pA0);  pA0 += 64;
            gld16(&sB[buf][tid * 8], pB0);  pB0 += 64;
        } else {
            gld16(&sA[buf][tid * 8], pA0);          pA0 += 64;
            gld16(&sA[buf][(256 + tid) * 8], pA1);  pA1 += 64;
            gld16(&sB[buf][(tid & (BN * 4 - 1)) * 8], pB0);  pB0 += 64;
        }
    };

    f32x16 acc0 = {0,0,0,0,0,0,0,0,0,0,0,0,0,0,0,0};
    f32x16 acc1 = {0,0,0,0,0,0,0,0,0,0,0,0,0,0,0,0};

    const int NT = K / 32;
    int cur = 0;
    stage(0);
    if constexpr (NBUF == 3) stage(1);
    for (int t = 0; t < NT; ++t) {
        if constexpr (NBUF == 2) {
            if (t + 1 < NT) {
                stage(cur ^ 1);
                asm volatile("s_waitcnt vmcnt(2)" ::: "memory");
            } else {
                asm volatile("s_waitcnt vmcnt(0)" ::: "memory");
            }
        } else {
            if (t + 2 < NT) {
                int nb3 = cur + 2; if (nb3 >= 3) nb3 -= 3;
                stage(nb3);
                asm volatile("s_waitcnt vmcnt(6)" ::: "memory");
            } else if (t + 1 < NT) {
                asm volatile("s_waitcnt vmcnt(3)" ::: "memory");
            } else {
                asm volatile("s_waitcnt vmcnt(0)" ::: "memory");
            }
        }
        __builtin_amdgcn_s_barrier();
        int rb = wc * 32 + l31;
        int swb = (rb >> 1) & 3;
        bf16x8 b0 = *(const bf16x8*)((const char*)sB[cur] + rb * 64 + ((hi ^ swb) << 4));
        bf16x8 b1 = *(const bf16x8*)((const char*)sB[cur] + rb * 64 + (((2 + hi) ^ swb) << 4));
        {
            int ra = wr * 64 + l31;
            int swa = (ra >> 1) & 3;
            bf16x8 a0 = *(const bf16x8*)((const char*)sA[cur] + ra * 64 + ((hi ^ swa) << 4));
            acc0 = __builtin_amdgcn_mfma_f32_32x32x16_bf16(a0, b0, acc0, 0, 0, 0);
            bf16x8 a1 = *(const bf16x8*)((const char*)sA[cur] + ra * 64 + (((2 + hi) ^ swa) << 4));
            acc0 = __builtin_amdgcn_mfma_f32_32x32x16_bf16(a1, b1, acc0, 0, 0, 0);
        }
        {
            int ra = wr * 64 + 32 + l31;
            int swa = (ra >> 1) & 3;
            bf16x8 a0 = *(const bf16x8*)((const char*)sA[cur] + ra * 64 + ((hi ^ swa) << 4));
            acc1 = __builtin_amdgcn_mfma_f32_32x32x16_bf16(a0, b0, acc1, 0, 0, 0);
            bf16x8 a1 = *(const bf16x8*)((const char*)sA[cur] + ra * 64 + (((2 + hi) ^ swa) << 4));
            acc1 = __builtin_amdgcn_mfma_f32_32x32x16_bf16(a1, b1, acc1, 0, 0, 0);
        }
        __builtin_amdgcn_s_barrier();
        ++cur; if (cur >= NBUF) cur = 0;
    }

    int n = bx * BN + wc * 32 + l31;
    int mb = by * 128 + wr * 64 + 4 * hi;
    if constexpr (EPI == 0) {
        int seg = n >> 10, nn = n & 1023;
        int h = nn >> 6, dd = nn & 63;
        int bb = (by * 128) >> 11;
        if (seg == 0) {
            float bs = bias[nn];
            short* p = outQ + (size_t)(bb * NHEAD + h) * SEQ * DK + dd;
#pragma unroll
            for (int i = 0; i < 2; ++i)
#pragma unroll
                for (int reg = 0; reg < 16; ++reg) {
                    int ss = (mb + i * 32 + (reg & 3) + 8 * (reg >> 2)) & 2047;
                    float v = (i == 0) ? acc0[reg] : acc1[reg];
                    p[(size_t)ss * DK] = f2bf((v + bs) * 0.18033688011112042f);
                }
        } else if (seg == 1) {
            float bs = bias2[nn];
            short* p = outK + (size_t)(bb * NHEAD + h) * SEQ * DK + dd;
#pragma unroll
            for (int i = 0; i < 2; ++i)
#pragma unroll
                for (int reg = 0; reg < 16; ++reg) {
                    int ss = (mb + i * 32 + (reg & 3) + 8 * (reg >> 2)) & 2047;
                    float v = (i == 0) ? acc0[reg] : acc1[reg];
                    p[(size_t)ss * DK] = f2bf(v + bs);
                }
        } else {
            float bs = bias3[nn];
            short* p = outV + ((size_t)(bb * NHEAD + h) * DK + dd) * SEQ;
#pragma unroll
            for (int i = 0; i < 2; ++i)
#pragma unroll
                for (int reg = 0; reg < 16; ++reg) {
                    int ss = (mb + i * 32 + (reg & 3) + 8 * (reg >> 2)) & 2047;
                    float v = (i == 0) ? acc0[reg] : acc1[reg];
                    p[ss] = f2bf(v + bs);
                }
        }
    } else if constexpr (EPI == 1) {
        float bs = bias[n];
#pragma unroll
        for (int i = 0; i < 2; ++i)
#pragma unroll
            for (int reg = 0; reg < 16; ++reg) {
                int m = mb + i * 32 + (reg & 3) + 8 * (reg >> 2);
                float v = (i == 0) ? acc0[reg] : acc1[reg];
                size_t idx = (size_t)m * N + n;
                outB[idx] = f2bf(v + bs + resid[idx]);
            }
    } else if constexpr (EPI == 3) {
        const short* rb16 = (const short*)resid;
        float bs = bias[n];
#pragma unroll
        for (int i = 0; i < 2; ++i)
#pragma unroll
            for (int reg = 0; reg < 16; ++reg) {
                int m = mb + i * 32 + (reg & 3) + 8 * (reg >> 2);
                float v = (i == 0) ? acc0[reg] : acc1[reg];
                size_t idx = (size_t)m * N + n;
                outF[idx] = v + bs + bf2f(rb16[idx]);
            }
    } else {
        float bs = bias[n];
#pragma unroll
        for (int i = 0; i < 2; ++i)
#pragma unroll
            for (int reg = 0; reg < 16; ++reg) {
                int m = mb + i * 32 + (reg & 3) + 8 * (reg >> 2);
                float v = (i == 0) ? acc0[reg] : acc1[reg];
                float r2 = v + bs;
                outB[(size_t)m * N + n] = f2bf(r2 > 0.f ? r2 : 0.f);
            }
    }
}

// ---------------- flash attention: r17/r18 config exactly (best measured: 45.9us) ----------------
// 8 waves = 4 q-groups x 2 k-halves, 512 threads, 128 q-rows/block, VGPR 48,
// 32 waves/CU. Per-lane lsum in VALU (Ls-MFMA killed twice: r10 occupancy,
// r19 scratch spill).
__global__ __launch_bounds__(512) void k_attn(const short* __restrict__ Q, const short* __restrict__ Kk,
                                              const short* __restrict__ Vt, short* __restrict__ Operm)
{
    __shared__ __align__(16) union {
        short kv[2][2][64 * 64];        // [buf][K/V][tile] 32 KB
        float mrg[4 * 64 * 33];         // merge scratch 33.8 KB
    } sU;
    int tid = threadIdx.x, lane = tid & 63;
    int wid = tid >> 6;
    int qg = wid >> 1, ks = wid & 1;
    int l31 = lane & 31, hi = lane >> 5;

    int orig = blockIdx.x + blockIdx.y * 32;
    int lg = (orig & 7) * 64 + (orig >> 3);   // 512 blocks: XCD gets 4 consecutive bh
    int bh = lg >> 4, qt = lg & 15;
    int b = bh >> 4, h = bh & 15;
    int q0 = qt * 128 + qg * 32;
    const short* Qp = Q + (size_t)bh * SEQ * DK;
    const short* Kp = Kk + (size_t)bh * SEQ * DK;
    const short* Vp = Vt + (size_t)bh * DK * SEQ;

    bf16x8 qf[4];
#pragma unroll
    for (int kb = 0; kb < 4; ++kb)
        qf[kb] = *(const bf16x8*)(Qp + (size_t)(q0 + l31) * DK + kb * 16 + hi * 8);

    int r0 = tid >> 3;
    int lb = ((tid & 7) ^ (r0 & 7)) << 4;
    const char* pK0 = (const char*)(Kp + (size_t)r0 * DK) + lb;
    const char* pV0 = (const char*)(Vp + (size_t)r0 * SEQ) + lb;

    auto stage = [&](int buf) {
        gld16(&sU.kv[buf][0][tid * 8], pK0);  pK0 += 8192;
        gld16(&sU.kv[buf][1][tid * 8], pV0);  pV0 += 128;
    };

    f32x16 Oa0 = {0,0,0,0,0,0,0,0,0,0,0,0,0,0,0,0};
    f32x16 Oa1 = {0,0,0,0,0,0,0,0,0,0,0,0,0,0,0,0};
    float lsum = 0.f;

    stage(0);
    const int NT = SEQ / 64;
    int krow = ks * 32 + l31;
    int sw = (l31 & 7) << 4;
    for (int t = 0; t < NT; ++t) {
        int cur = t & 1;
        if (t + 1 < NT) {
            stage(cur ^ 1);
            asm volatile("s_waitcnt vmcnt(2)" ::: "memory");   // tile t's 2 loads done
        } else {
            asm volatile("s_waitcnt vmcnt(0)" ::: "memory");
        }
        __builtin_amdgcn_s_barrier();
        const char* sKc = (const char*)sU.kv[cur][0];
        const char* sVc = (const char*)sU.kv[cur][1];

        f32x16 sc = {0,0,0,0,0,0,0,0,0,0,0,0,0,0,0,0};
        __builtin_amdgcn_s_setprio(1);
#pragma unroll
        for (int kb = 0; kb < 4; ++kb) {
            int cb = (kb * 32 + hi * 16) ^ sw;
            bf16x8 kf = *(const bf16x8*)(sKc + krow * 128 + cb);
            sc = __builtin_amdgcn_mfma_f32_32x32x16_bf16(kf, qf[kb], sc, 0, 0, 0);
        }
        __builtin_amdgcn_s_setprio(0);

        unsigned W[4][2];
#pragma unroll
        for (int tt = 0; tt < 4; ++tt) {
            float pa_ = EXP2(sc[4*tt+0]), pb_ = EXP2(sc[4*tt+1]);
            float pc_ = EXP2(sc[4*tt+2]), pd_ = EXP2(sc[4*tt+3]);
            lsum += (pa_ + pb_) + (pc_ + pd_);
            asm("v_cvt_pk_bf16_f32 %0, %1, %2" : "=v"(W[tt][0]) : "v"(pa_), "v"(pb_));
            asm("v_cvt_pk_bf16_f32 %0, %1, %2" : "=v"(W[tt][1]) : "v"(pc_), "v"(pd_));
        }

        auto pv_step = [&](unsigned a0, unsigned a1, unsigned b0v, unsigned b1v, int kslice) {
            asm("v_permlane32_swap_b32 %0, %1" : "+v"(a0), "+v"(b0v));
            asm("v_permlane32_swap_b32 %0, %1" : "+v"(a1), "+v"(b1v));
            union { unsigned u[4]; bf16x8 v; } pa;
            pa.u[0] = a0; pa.u[1] = a1; pa.u[2] = b0v; pa.u[3] = b1v;
            int cb = (kslice * 32 + hi * 16) ^ sw;
            bf16x8 vf0 = *(const bf16x8*)(sVc + l31 * 128 + cb);
            bf16x8 vf1 = *(const bf16x8*)(sVc + (32 + l31) * 128 + cb);
            Oa0 = __builtin_amdgcn_mfma_f32_32x32x16_bf16(pa.v, vf0, Oa0, 0, 0, 0);
            Oa1 = __builtin_amdgcn_mfma_f32_32x32x16_bf16(pa.v, vf1, Oa1, 0, 0, 0);
        };
        __builtin_amdgcn_s_setprio(1);
        pv_step(W[0][0], W[0][1], W[1][0], W[1][1], ks * 2 + 0);
        pv_step(W[2][0], W[2][1], W[3][0], W[3][1], ks * 2 + 1);
        __builtin_amdgcn_s_setprio(0);
        __builtin_amdgcn_s_barrier();
    }

    lsum += __shfl_xor(lsum, 32, 64);

    float* mrg = sU.mrg;
    if (ks == 1) {
        float* m0 = mrg + (qg * 64 + lane) * 33;
#pragma unroll
        for (int i = 0; i < 16; ++i) m0[i] = Oa0[i];
#pragma unroll
        for (int i = 0; i < 16; ++i) m0[16 + i] = Oa1[i];
        m0[32] = lsum;
    }
    __syncthreads();
    if (ks == 0) {
        const float* m0 = mrg + (qg * 64 + lane) * 33;
#pragma unroll
        for (int i = 0; i < 16; ++i) Oa0[i] += m0[i];
#pragma unroll
        for (int i = 0; i < 16; ++i) Oa1[i] += m0[16 + i];
        lsum += m0[32];

        float rlv[16];
#pragma unroll
        for (int tt = 0; tt < 4; ++tt)
#pragma unroll
            for (int rr = 0; rr < 4; ++rr) {
                float ts = __shfl(lsum, 4 * hi + 8 * tt + rr, 64);
                rlv[4 * tt + rr] = 1.f / ts;
            }

        int qcol = (q0 & 1023) + 4 * hi;
        int qhi = q0 >> 10;
#pragma unroll
        for (int db = 0; db < 2; ++db) {
            const f32x16& O = db ? Oa1 : Oa0;
            int dd = db * 32 + l31;
            size_t rowoff = ((size_t)b * SEQ + h * 128 + 2 * dd + qhi) * D_MODEL + qcol;
#pragma unroll
            for (int tt = 0; tt < 4; ++tt) {
                s16x4 o;
                o.x = f2bf(O[4*tt+0] * rlv[4*tt+0]);
                o.y = f2bf(O[4*tt+1] * rlv[4*tt+1]);
                o.z = f2bf(O[4*tt+2] * rlv[4*tt+2]);
                o.w = f2bf(O[4*tt+3] * rlv[4*tt+3]);
                *(s16x4*)(Operm + rowoff + 8 * tt) = o;
            }
        }
    }
}

extern "C" void kernel_launch(void* const* d_in, const int* in_sizes, int n_in,
                              void* d_out, int out_size, void* d_ws, size_t ws_size,
                              hipStream_t stream)
{
    const float* x   = (const float*)d_in[0];
    const float* Wq  = (const float*)d_in[1];
    const float* bq  = (const float*)d_in[2];
    const float* Wk  = (const float*)d_in[3];
    const float* bk  = (const float*)d_in[4];
    const float* Wv  = (const float*)d_in[5];
    const float* bv  = (const float*)d_in[6];
    const float* Wo  = (const float*)d_in[7];
    const float* bo  = (const float*)d_in[8];
    const float* g1  = (const float*)d_in[9];
    const float* b1l = (const float*)d_in[10];
    const float* g2  = (const float*)d_in[11];
    const float* b2l = (const float*)d_in[12];
    const float* W1  = (const float*)d_in[13];
    const float* b1  = (const float*)d_in[14];
    const float* W2  = (const float*)d_in[15];
    const float* b2  = (const float*)d_in[16];
    float* out = (float*)d_out;

    char* ws = (char*)d_ws;
    size_t off = 0;
    auto alloc = [&](size_t bytes) {
        char* p = ws + off;
        off += (bytes + 255) & ~(size_t)255;
        return p;
    };
    short* WqkvT = (short*)alloc((size_t)3072 * 1024 * 2);
    short* WoT   = (short*)alloc((size_t)1024 * 1024 * 2);
    short* W1T   = (short*)alloc((size_t)2048 * 1024 * 2);
    short* W2T   = (short*)alloc((size_t)1024 * 2048 * 2);
    short* Y     = (short*)alloc((size_t)NTOK * 1024 * 2);
    short* Qb    = (short*)alloc((size_t)NTOK * 1024 * 2);
    short* Kb    = (short*)alloc((size_t)NTOK * 1024 * 2);
    short* Vtb   = (short*)alloc((size_t)NTOK * 1024 * 2);
    short* Operm = (short*)alloc((size_t)NTOK * 1024 * 2);
    short* Xb    = (short*)alloc((size_t)NTOK * 1024 * 2);   // bf16 x2 residual
    short* F1    = (short*)alloc((size_t)NTOK * 2048 * 2);

    // fused prologue: 6 weight transposes + LN1 in one dispatch
    TP6 tp;
    tp.src[0] = Wq; tp.dst[0] = WqkvT;                tp.K[0] = 1024; tp.N[0] = 1024; tp.nx[0] = 32;
    tp.src[1] = Wk; tp.dst[1] = WqkvT + 1024 * 1024;  tp.K[1] = 1024; tp.N[1] = 1024; tp.nx[1] = 32;
    tp.src[2] = Wv; tp.dst[2] = WqkvT + 2048 * 1024;  tp.K[2] = 1024; tp.N[2] = 1024; tp.nx[2] = 32;
    tp.src[3] = Wo; tp.dst[3] = WoT;                  tp.K[3] = 1024; tp.N[3] = 1024; tp.nx[3] = 32;
    tp.src[4] = W1; tp.dst[4] = W1T;                  tp.K[4] = 1024; tp.N[4] = 2048; tp.nx[4] = 64;
    tp.src[5] = W2; tp.dst[5] = W2T;                  tp.K[5] = 2048; tp.N[5] = 1024; tp.nx[5] = 32;
    k_prolog<<<8192 + 1024, 256, 0, stream>>>(tp, x, g1, b1l, Y);

    // fused QKV GEMM (4096 x 3072 x 1024), 512 threads, 8 waves, 2-buf
    k_gemm<0,128,512><<<dim3(24, 32), 512, 0, stream>>>(Y, WqkvT, 3072, 1024,
        bq, bk, bv, nullptr, nullptr, nullptr, Qb, Kb, Vtb);

    // attention (512 blocks, 512 threads: 4 q-groups x 2 k-halves)
    k_attn<<<dim3(32, 16), 512, 0, stream>>>(Qb, Kb, Vtb, Operm);

    // Wo GEMM + bias + residual(x) -> Xb (bf16)   [BN=64 -> 512 blocks]
    k_gemm<1,64,256><<<dim3(16, 32), 256, 0, stream>>>(Operm, WoT, 1024, 1024,
        bo, nullptr, nullptr, x, nullptr, Xb, nullptr, nullptr, nullptr);

    // LN2: Xb (bf16) -> Y (bf16)
    k_layernorm_bf<<<NTOK / 4, 256, 0, stream>>>(Xb, g2, b2l, Y);

    // FFN1: relu(Y @ W1 + b1) -> F1 (bf16), 512 threads, 8 waves, 2-buf
    k_gemm<2,128,512><<<dim3(16, 32), 512, 0, stream>>>(Y, W1T, 2048, 1024,
        b1, nullptr, nullptr, nullptr, nullptr, F1, nullptr, nullptr, nullptr);

    // FFN2: F1 @ W2 + b2 + Xb(bf16) -> out (fp32)   [BN=64 -> 512 blocks]
    k_gemm<3,64,256><<<dim3(16, 32), 256, 0, stream>>>(F1, W2T, 1024, 2048,
        b2, nullptr, nullptr, (const float*)Xb, out, nullptr, nullptr, nullptr, nullptr);
}